// Round 13
// baseline (119.765 us; speedup 1.0000x reference)
//
#include <hip/hip_runtime.h>

#define N_ROWS 8192
#define BM 128                   // rows per block
#define SEG 512                  // cols per block
#define TILE 64                  // cols per tile
#define NTILE (SEG / TILE)       // 8
#define NSEG (N_ROWS / SEG)      // 16
#define NPART NSEG               // 16 partials per row
#define KEXP 20.60992915f        // log2(e)/TAU

typedef __attribute__((ext_vector_type(8))) short short8;
typedef __attribute__((ext_vector_type(4))) float f32x4;

__device__ __forceinline__ unsigned short f2bf(float x) {
  unsigned int u = __float_as_uint(x);
  unsigned int r = (u + 0x7fffu + ((u >> 16) & 1u)) >> 16;
  return (unsigned short)r;
}

__device__ __forceinline__ float fast_exp2(float x) {
  float r;
  asm("v_exp_f32 %0, %1" : "=v"(r) : "v"(x));
  return r;
}

// Kernel 1: L2-normalize rows; write fn in MFMA-FRAGMENT order:
// fragment (row-group G = row>>4, k-step ks) = contiguous 1KB at
// G*4096 + ks*1024 + mfma_lane*16. fnA scaled by log2(e)/tau, fnB unscaled.
__global__ __launch_bounds__(256) void knorm(const float* __restrict__ feat,
                                             unsigned int* __restrict__ fnA,
                                             unsigned int* __restrict__ fnB) {
  const int wid = threadIdx.x >> 6;
  const int lane = threadIdx.x & 63;
  const int row = blockIdx.x * 4 + wid;
  const float2 v = *(const float2*)(feat + (size_t)row * 128 + lane * 2);
  float s = v.x * v.x + v.y * v.y;
#pragma unroll
  for (int m = 1; m < 64; m <<= 1) s += __shfl_xor(s, m);
  const float inv = 1.0f / fmaxf(sqrtf(s), 1e-12f);
  const float x = v.x * inv, y = v.y * inv;
  const int cc = lane >> 2;  // 16B chunk of this row held by this lane
  const int idx = ((row >> 4) << 10) + ((cc >> 2) << 8) + ((cc & 3) << 6) +
                  ((row & 15) << 2) + (lane & 3);
  fnB[idx] = (unsigned int)f2bf(x) | ((unsigned int)f2bf(y) << 16);
  fnA[idx] = (unsigned int)f2bf(x * KEXP) | ((unsigned int)f2bf(y * KEXP) << 16);
}

// Kernel 2 (REAL, byte-identical to R12): no-LDS, barrier-free.
__global__ __launch_bounds__(256, 4) void ksim(const unsigned int* __restrict__ fnA,
                                               const unsigned int* __restrict__ fnB,
                                               const float* __restrict__ alphap,
                                               float* __restrict__ posP,
                                               float* __restrict__ totP) {
  const int tid = threadIdx.x;
  const int lane = tid & 63;
  const int wid = tid >> 6;
  const int r0 = blockIdx.x * BM;
  const int c0 = blockIdx.y * SEG;
  const float alphaK = alphap[0] * KEXP;

  const char* __restrict__ FA = (const char*)fnA;
  const char* __restrict__ FB = (const char*)fnB;

  short8 aR[2][4];
  {
    const int G0 = (r0 + wid * 32) >> 4;
#pragma unroll
    for (int m = 0; m < 2; m++)
#pragma unroll
      for (int ks = 0; ks < 4; ks++)
        aR[m][ks] = *(const short8*)(FA + (size_t)(G0 + m) * 4096 + ks * 1024 + lane * 16);
  }

  float pp[2][4] = {{0.f}}, tp[2][4] = {{0.f}};

#pragma unroll 1
  for (int it = 0; it < NTILE; ++it) {
    const char* Bb = FB + (size_t)((c0 >> 4) + it * 4) * 4096 + lane * 16;

    f32x4 acc[2][4];
#pragma unroll
    for (int m = 0; m < 2; m++)
#pragma unroll
      for (int n = 0; n < 4; n++) acc[m][n] = (f32x4){0.f, 0.f, 0.f, 0.f};

#pragma unroll
    for (int ks = 0; ks < 4; ks++) {
      const short8 b0 = *(const short8*)(Bb + 0 * 4096 + ks * 1024);
      const short8 b1 = *(const short8*)(Bb + 1 * 4096 + ks * 1024);
      const short8 b2 = *(const short8*)(Bb + 2 * 4096 + ks * 1024);
      const short8 b3 = *(const short8*)(Bb + 3 * 4096 + ks * 1024);
#pragma unroll
      for (int m = 0; m < 2; m++) {
        acc[m][0] = __builtin_amdgcn_mfma_f32_16x16x32_bf16(aR[m][ks], b0, acc[m][0], 0, 0, 0);
        acc[m][1] = __builtin_amdgcn_mfma_f32_16x16x32_bf16(aR[m][ks], b1, acc[m][1], 0, 0, 0);
        acc[m][2] = __builtin_amdgcn_mfma_f32_16x16x32_bf16(aR[m][ks], b2, acc[m][2], 0, 0, 0);
        acc[m][3] = __builtin_amdgcn_mfma_f32_16x16x32_bf16(aR[m][ks], b3, acc[m][3], 0, 0, 0);
      }
    }

    const int cb = c0 + it * TILE;
#pragma unroll
    for (int m = 0; m < 2; m++) {
      const int grb = r0 + wid * 32 + m * 16;
#pragma unroll
      for (int n = 0; n < 4; n++) {
        const int gcb = cb + n * 16;
        const f32x4 a = acc[m][n];
        if (grb == gcb) {
          const int gr0 = (lane >> 4) << 2;
          const int gcl = lane & 15;
#pragma unroll
          for (int r = 0; r < 4; r++) {
            const float e = fast_exp2(a[r]);
            const float ev = (gr0 + r == gcl) ? 0.0f : e;
            tp[m][r] += ev;
            pp[m][r] += (a[r] >= alphaK) ? ev : 0.0f;
          }
        } else {
#pragma unroll
          for (int r = 0; r < 4; r++) {
            const float e = fast_exp2(a[r]);
            tp[m][r] += e;
            pp[m][r] += (a[r] >= alphaK) ? e : 0.0f;
          }
        }
      }
    }
  }

#pragma unroll
  for (int m = 0; m < 2; m++)
#pragma unroll
    for (int r = 0; r < 4; r++) {
      float p = pp[m][r], t = tp[m][r];
#pragma unroll
      for (int msk = 1; msk < 16; msk <<= 1) {
        p += __shfl_xor(p, msk);
        t += __shfl_xor(t, msk);
      }
      if ((lane & 15) == 0) {
        const int row = r0 + wid * 32 + m * 16 + ((lane >> 4) << 2) + r;
        posP[blockIdx.y * N_ROWS + row] = p;
        totP[blockIdx.y * N_ROWS + row] = t;
      }
    }
}

// Diagnostic arms (write scratch only). MODE 0 = full epilogue (2x real work,
// top-5 visible -> direct counters). MODE 1 = loads+MFMA with epilogue
// stripped to tot += a[r] (isolates load/MFMA-bound time; acc stays live).
template <int MODE>
__global__ __launch_bounds__(256, 4) void kdiag(const unsigned int* __restrict__ fnA,
                                                const unsigned int* __restrict__ fnB,
                                                const float* __restrict__ alphap,
                                                float* __restrict__ sposP,
                                                float* __restrict__ stotP) {
  const int tid = threadIdx.x;
  const int lane = tid & 63;
  const int wid = tid >> 6;
  const int r0 = blockIdx.x * BM;
  const float alphaK = alphap[0] * KEXP;

  const char* __restrict__ FA = (const char*)fnA;
  const char* __restrict__ FB = (const char*)fnB;

  short8 aR[2][4];
  {
    const int G0 = (r0 + wid * 32) >> 4;
#pragma unroll
    for (int m = 0; m < 2; m++)
#pragma unroll
      for (int ks = 0; ks < 4; ks++)
        aR[m][ks] = *(const short8*)(FA + (size_t)(G0 + m) * 4096 + ks * 1024 + lane * 16);
  }

#pragma unroll 1
  for (int rep = 0; rep < 2; ++rep) {
    const int seg = (blockIdx.y + rep * 8) & 15;
    const int c0 = seg * SEG;
    float pp[2][4] = {{0.f}}, tp[2][4] = {{0.f}};

#pragma unroll 1
    for (int it = 0; it < NTILE; ++it) {
      const char* Bb = FB + (size_t)((c0 >> 4) + it * 4) * 4096 + lane * 16;

      f32x4 acc[2][4];
#pragma unroll
      for (int m = 0; m < 2; m++)
#pragma unroll
        for (int n = 0; n < 4; n++) acc[m][n] = (f32x4){0.f, 0.f, 0.f, 0.f};

#pragma unroll
      for (int ks = 0; ks < 4; ks++) {
        const short8 b0 = *(const short8*)(Bb + 0 * 4096 + ks * 1024);
        const short8 b1 = *(const short8*)(Bb + 1 * 4096 + ks * 1024);
        const short8 b2 = *(const short8*)(Bb + 2 * 4096 + ks * 1024);
        const short8 b3 = *(const short8*)(Bb + 3 * 4096 + ks * 1024);
#pragma unroll
        for (int m = 0; m < 2; m++) {
          acc[m][0] = __builtin_amdgcn_mfma_f32_16x16x32_bf16(aR[m][ks], b0, acc[m][0], 0, 0, 0);
          acc[m][1] = __builtin_amdgcn_mfma_f32_16x16x32_bf16(aR[m][ks], b1, acc[m][1], 0, 0, 0);
          acc[m][2] = __builtin_amdgcn_mfma_f32_16x16x32_bf16(aR[m][ks], b2, acc[m][2], 0, 0, 0);
          acc[m][3] = __builtin_amdgcn_mfma_f32_16x16x32_bf16(aR[m][ks], b3, acc[m][3], 0, 0, 0);
        }
      }

      const int cb = c0 + it * TILE;
#pragma unroll
      for (int m = 0; m < 2; m++) {
        const int grb = r0 + wid * 32 + m * 16;
#pragma unroll
        for (int n = 0; n < 4; n++) {
          const f32x4 a = acc[m][n];
          if (MODE == 1) {
#pragma unroll
            for (int r = 0; r < 4; r++) tp[m][r] += a[r];  // keeps acc live, no exp
          } else {
            const int gcb = cb + n * 16;
            if (grb == gcb) {
              const int gr0 = (lane >> 4) << 2;
              const int gcl = lane & 15;
#pragma unroll
              for (int r = 0; r < 4; r++) {
                const float e = fast_exp2(a[r]);
                const float ev = (gr0 + r == gcl) ? 0.0f : e;
                tp[m][r] += ev;
                pp[m][r] += (a[r] >= alphaK) ? ev : 0.0f;
              }
            } else {
#pragma unroll
              for (int r = 0; r < 4; r++) {
                const float e = fast_exp2(a[r]);
                tp[m][r] += e;
                pp[m][r] += (a[r] >= alphaK) ? e : 0.0f;
              }
            }
          }
        }
      }
    }

#pragma unroll
    for (int m = 0; m < 2; m++)
#pragma unroll
      for (int r = 0; r < 4; r++) {
        float p = pp[m][r], t = tp[m][r];
#pragma unroll
        for (int msk = 1; msk < 16; msk <<= 1) {
          p += __shfl_xor(p, msk);
          t += __shfl_xor(t, msk);
        }
        if ((lane & 15) == 0) {
          const int row = r0 + wid * 32 + m * 16 + ((lane >> 4) << 2) + r;
          sposP[(rep * 16 + seg) * N_ROWS + row] = p;
          stotP[(rep * 16 + seg) * N_ROWS + row] = t;
        }
      }
  }
}

// Kernel 3a: per-row loss term, 128-row blocks -> 64 partial sums.
__global__ __launch_bounds__(128) void kred1(const float* __restrict__ posP,
                                             const float* __restrict__ totP,
                                             float* __restrict__ bp) {
  const int t = threadIdx.x;
  const int row = blockIdx.x * 128 + t;
  float pos = 0.f, tot = 0.f;
#pragma unroll
  for (int c = 0; c < NPART; c++) {
    pos += posP[c * N_ROWS + row];
    tot += totP[c * N_ROWS + row];
  }
  float term = __logf(tot + 2e-10f) - __logf(pos + 1e-10f);
#pragma unroll
  for (int m = 1; m < 64; m <<= 1) term += __shfl_xor(term, m);
  __shared__ float s2[2];
  if ((t & 63) == 0) s2[t >> 6] = term;
  __syncthreads();
  if (t == 0) bp[blockIdx.x] = s2[0] + s2[1];
}

// Kernel 3b: final mean.
__global__ void kred2(const float* __restrict__ bp, float* __restrict__ out) {
  const int l = threadIdx.x;
  float v = bp[l];
#pragma unroll
  for (int m = 1; m < 64; m <<= 1) v += __shfl_xor(v, m);
  if (l == 0) out[0] = v * (1.0f / 8192.0f);
}

extern "C" void kernel_launch(void* const* d_in, const int* in_sizes, int n_in,
                              void* d_out, int out_size, void* d_ws, size_t ws_size,
                              hipStream_t stream) {
  const float* feat = (const float*)d_in[0];
  const float* alphap = (const float*)d_in[1];
  char* ws = (char*)d_ws;
  unsigned int* fnA = (unsigned int*)ws;                    // 2 MB frag-ordered bf16, x log2e/tau
  unsigned int* fnB = (unsigned int*)(ws + (2u << 20));     // 2 MB frag-ordered bf16
  float* posP = (float*)(ws + (4u << 20));                  // 512 KB (16 x 8192)
  float* totP = (float*)(ws + (5u << 20));                  // 512 KB
  float* bp = (float*)(ws + (6u << 20));                    // 256 B
  float* sposP = (float*)(ws + (8u << 20));                 // 1 MB scratch (diag)
  float* stotP = (float*)(ws + (9u << 20));                 // 1 MB scratch (diag)
  float* sposB = (float*)(ws + (10u << 20));                // 1 MB scratch (diag B)
  float* stotB = (float*)(ws + (11u << 20));                // 1 MB scratch (diag B)
  float* out = (float*)d_out;

  knorm<<<dim3(N_ROWS / 4), dim3(256), 0, stream>>>(feat, fnA, fnB);
  ksim<<<dim3(N_ROWS / BM, NSEG), dim3(256), 0, stream>>>(fnA, fnB, alphap, posP, totP);
  kred1<<<dim3(N_ROWS / 128), dim3(128), 0, stream>>>(posP, totP, bp);
  kred2<<<dim3(1), dim3(64), 0, stream>>>(bp, out);
  // Diagnostics after the real path (scratch only).
  kdiag<0><<<dim3(N_ROWS / BM, NSEG), dim3(256), 0, stream>>>(fnA, fnB, alphap, sposP, stotP);
  kdiag<1><<<dim3(N_ROWS / BM, NSEG), dim3(256), 0, stream>>>(fnA, fnB, alphap, sposB, stotB);
}

// Round 14
// 35.127 us; speedup vs baseline: 3.4095x; 3.4095x over previous
//
#include <hip/hip_runtime.h>

#define N_ROWS 8192
#define BM 128                   // rows per block
#define SEG 512                  // cols per block
#define TILE 64                  // cols per tile
#define NTILE (SEG / TILE)       // 8
#define NSEG (N_ROWS / SEG)      // 16
#define NPART NSEG               // 16 partials per row
#define KEXP 20.60992915f        // log2(e)/TAU

typedef __attribute__((ext_vector_type(4))) float f32x4;
typedef __attribute__((ext_vector_type(2))) long long2v;

__device__ __forceinline__ float fast_exp2(float x) {
  float r;
  asm("v_exp_f32 %0, %1" : "=v"(r) : "v"(x));
  return r;
}

// Kernel 1: L2-normalize rows; write fp8 e4m3 in MFMA-FRAGMENT-PAIR order.
// Element (row,k): G=row>>4, p=k>>6, h=(k>>5)&1, ksub=(k>>3)&3, kk=k&7.
// byte = G*2048 + p*1024 + ksub*256 + (row&15)*16 + h*8 + kk.
// A lane's 16B in ksim = [frag ks=2p 8B][frag ks=2p+1 8B] -> one long2 load.
// fnA scaled by log2(e)/tau, fnB unscaled.
__global__ __launch_bounds__(256) void knorm(const float* __restrict__ feat,
                                             unsigned short* __restrict__ fnA,
                                             unsigned short* __restrict__ fnB) {
  const int wid = threadIdx.x >> 6;
  const int lane = threadIdx.x & 63;
  const int row = blockIdx.x * 4 + wid;
  const float2 v = *(const float2*)(feat + (size_t)row * 128 + lane * 2);
  float s = v.x * v.x + v.y * v.y;
#pragma unroll
  for (int m = 1; m < 64; m <<= 1) s += __shfl_xor(s, m);
  const float inv = 1.0f / fmaxf(sqrtf(s), 1e-12f);
  const float x = v.x * inv, y = v.y * inv;
  const int k = lane * 2;  // this thread's two consecutive k elements
  const int p = k >> 6, h = (k >> 5) & 1, ksub = (k >> 3) & 3, kk = k & 7;
  const int byteoff = ((row >> 4) << 11) + (p << 10) + (ksub << 8) +
                      ((row & 15) << 4) + (h << 3) + kk;  // kk even
  const unsigned int pkB = __builtin_amdgcn_cvt_pk_fp8_f32(x, y, 0, 0);
  const unsigned int pkA = __builtin_amdgcn_cvt_pk_fp8_f32(x * KEXP, y * KEXP, 0, 0);
  fnB[byteoff >> 1] = (unsigned short)pkB;
  fnA[byteoff >> 1] = (unsigned short)pkA;
}

// Kernel 2: no-LDS, barrier-free, fp8. B fragments direct from frag-ordered
// global: one 16B long2 load = TWO k-step fragments (half the loads of bf16).
// Wave = 32 rows (m=2) x 64 cols (n=4); 8 loads + 32 MFMA per tile.
__global__ __launch_bounds__(256, 4) void ksim(const unsigned short* __restrict__ fnA,
                                               const unsigned short* __restrict__ fnB,
                                               const float* __restrict__ alphap,
                                               float* __restrict__ posP,
                                               float* __restrict__ totP) {
  const int tid = threadIdx.x;
  const int lane = tid & 63;
  const int wid = tid >> 6;
  const int r0 = blockIdx.x * BM;
  const int c0 = blockIdx.y * SEG;
  const float alphaK = alphap[0] * KEXP;

  const char* __restrict__ FA = (const char*)fnA;
  const char* __restrict__ FB = (const char*)fnB;

  // A fragments: 2 m-frags x 4 ks (8B each), loaded as 2x2 16B pair-loads.
  long aR[2][4];
  {
    const int G0 = (r0 + wid * 32) >> 4;
#pragma unroll
    for (int m = 0; m < 2; m++)
#pragma unroll
      for (int p = 0; p < 2; p++) {
        const long2v t = *(const long2v*)(FA + (size_t)(G0 + m) * 2048 + p * 1024 + lane * 16);
        aR[m][2 * p] = t[0];
        aR[m][2 * p + 1] = t[1];
      }
  }

  float pp[2][4] = {{0.f}}, tp[2][4] = {{0.f}};

#pragma unroll 1
  for (int it = 0; it < NTILE; ++it) {
    const char* Bb = FB + (size_t)((c0 >> 4) + it * 4) * 2048 + lane * 16;

    f32x4 acc[2][4];
#pragma unroll
    for (int m = 0; m < 2; m++)
#pragma unroll
      for (int n = 0; n < 4; n++) acc[m][n] = (f32x4){0.f, 0.f, 0.f, 0.f};

#pragma unroll
    for (int p = 0; p < 2; p++) {
      const long2v b0 = *(const long2v*)(Bb + 0 * 2048 + p * 1024);
      const long2v b1 = *(const long2v*)(Bb + 1 * 2048 + p * 1024);
      const long2v b2 = *(const long2v*)(Bb + 2 * 2048 + p * 1024);
      const long2v b3 = *(const long2v*)(Bb + 3 * 2048 + p * 1024);
#pragma unroll
      for (int m = 0; m < 2; m++) {
        acc[m][0] = __builtin_amdgcn_mfma_f32_16x16x32_fp8_fp8(aR[m][2 * p], b0[0], acc[m][0], 0, 0, 0);
        acc[m][1] = __builtin_amdgcn_mfma_f32_16x16x32_fp8_fp8(aR[m][2 * p], b1[0], acc[m][1], 0, 0, 0);
        acc[m][2] = __builtin_amdgcn_mfma_f32_16x16x32_fp8_fp8(aR[m][2 * p], b2[0], acc[m][2], 0, 0, 0);
        acc[m][3] = __builtin_amdgcn_mfma_f32_16x16x32_fp8_fp8(aR[m][2 * p], b3[0], acc[m][3], 0, 0, 0);
        acc[m][0] = __builtin_amdgcn_mfma_f32_16x16x32_fp8_fp8(aR[m][2 * p + 1], b0[1], acc[m][0], 0, 0, 0);
        acc[m][1] = __builtin_amdgcn_mfma_f32_16x16x32_fp8_fp8(aR[m][2 * p + 1], b1[1], acc[m][1], 0, 0, 0);
        acc[m][2] = __builtin_amdgcn_mfma_f32_16x16x32_fp8_fp8(aR[m][2 * p + 1], b2[1], acc[m][2], 0, 0, 0);
        acc[m][3] = __builtin_amdgcn_mfma_f32_16x16x32_fp8_fp8(aR[m][2 * p + 1], b3[1], acc[m][3], 0, 0, 0);
      }
    }

    // Epilogue: a = sim*log2e/tau (A pre-scaled). e = 2^a; tot += e; pos += e if a>=alphaK.
    const int cb = c0 + it * TILE;
#pragma unroll
    for (int m = 0; m < 2; m++) {
      const int grb = r0 + wid * 32 + m * 16;
#pragma unroll
      for (int n = 0; n < 4; n++) {
        const int gcb = cb + n * 16;
        const f32x4 a = acc[m][n];
        if (grb == gcb) {  // diagonal fragment: self-exclusion
          const int gr0 = (lane >> 4) << 2;
          const int gcl = lane & 15;
#pragma unroll
          for (int r = 0; r < 4; r++) {
            const float e = fast_exp2(a[r]);
            const float ev = (gr0 + r == gcl) ? 0.0f : e;
            tp[m][r] += ev;
            pp[m][r] += (a[r] >= alphaK) ? ev : 0.0f;
          }
        } else {
#pragma unroll
          for (int r = 0; r < 4; r++) {
            const float e = fast_exp2(a[r]);
            tp[m][r] += e;
            pp[m][r] += (a[r] >= alphaK) ? e : 0.0f;
          }
        }
      }
    }
  }

#pragma unroll
  for (int m = 0; m < 2; m++)
#pragma unroll
    for (int r = 0; r < 4; r++) {
      float p = pp[m][r], t = tp[m][r];
#pragma unroll
      for (int msk = 1; msk < 16; msk <<= 1) {
        p += __shfl_xor(p, msk);
        t += __shfl_xor(t, msk);
      }
      if ((lane & 15) == 0) {
        const int row = r0 + wid * 32 + m * 16 + ((lane >> 4) << 2) + r;
        posP[blockIdx.y * N_ROWS + row] = p;
        totP[blockIdx.y * N_ROWS + row] = t;
      }
    }
}

// Kernel 3a: per-row loss term, 128-row blocks -> 64 partial sums.
__global__ __launch_bounds__(128) void kred1(const float* __restrict__ posP,
                                             const float* __restrict__ totP,
                                             float* __restrict__ bp) {
  const int t = threadIdx.x;
  const int row = blockIdx.x * 128 + t;
  float pos = 0.f, tot = 0.f;
#pragma unroll
  for (int c = 0; c < NPART; c++) {
    pos += posP[c * N_ROWS + row];
    tot += totP[c * N_ROWS + row];
  }
  float term = __logf(tot + 2e-10f) - __logf(pos + 1e-10f);
#pragma unroll
  for (int m = 1; m < 64; m <<= 1) term += __shfl_xor(term, m);
  __shared__ float s2[2];
  if ((t & 63) == 0) s2[t >> 6] = term;
  __syncthreads();
  if (t == 0) bp[blockIdx.x] = s2[0] + s2[1];
}

// Kernel 3b: final mean.
__global__ void kred2(const float* __restrict__ bp, float* __restrict__ out) {
  const int l = threadIdx.x;
  float v = bp[l];
#pragma unroll
  for (int m = 1; m < 64; m <<= 1) v += __shfl_xor(v, m);
  if (l == 0) out[0] = v * (1.0f / 8192.0f);
}

extern "C" void kernel_launch(void* const* d_in, const int* in_sizes, int n_in,
                              void* d_out, int out_size, void* d_ws, size_t ws_size,
                              hipStream_t stream) {
  const float* feat = (const float*)d_in[0];
  const float* alphap = (const float*)d_in[1];
  char* ws = (char*)d_ws;
  unsigned short* fnA = (unsigned short*)ws;                // 1 MB fp8 frag-paired, x log2e/tau
  unsigned short* fnB = (unsigned short*)(ws + (1u << 20)); // 1 MB fp8 frag-paired
  float* posP = (float*)(ws + (2u << 20));                  // 512 KB (16 x 8192)
  float* totP = (float*)(ws + (3u << 20));                  // 512 KB
  float* bp = (float*)(ws + (4u << 20));                    // 256 B
  float* out = (float*)d_out;

  knorm<<<dim3(N_ROWS / 4), dim3(256), 0, stream>>>(feat, fnA, fnB);
  ksim<<<dim3(N_ROWS / BM, NSEG), dim3(256), 0, stream>>>(fnA, fnB, alphap, posP, totP);
  kred1<<<dim3(N_ROWS / 128), dim3(128), 0, stream>>>(posP, totP, bp);
  kred2<<<dim3(1), dim3(64), 0, stream>>>(bp, out);
}